// Round 3
// baseline (18847.720 us; speedup 1.0000x reference)
//
#include <hip/hip_runtime.h>
#include <hip/hip_bf16.h>
#include <hip/hip_cooperative_groups.h>

namespace cg = cooperative_groups;

#define N_NODES 20000
#define N_EDGES 320000
#define BATCH   64
#define N_IN    128
#define N_OUT   256
#define CAP     64
#define ITERS   150
#define LEAK    0.01f

#define NBLOCKS   1024
#define NTHREADS  256
#define NWAVES    (NBLOCKS * 4)           // 4096 waves
#define NPW       5                       // ceil(20000/4096) nodes per wave

// ---------------------------------------------------------------------------
// init: h0 = 0, bin = bias broadcast, cnt = 0
// ---------------------------------------------------------------------------
__global__ void init_kernel(float* __restrict__ h0, float* __restrict__ bin,
                            int* __restrict__ cnt, const float* __restrict__ biases) {
    int idx = blockIdx.x * blockDim.x + threadIdx.x;
    int total = N_NODES * BATCH;
    for (int i = idx; i < total; i += gridDim.x * blockDim.x) {
        h0[i]  = 0.0f;
        bin[i] = biases[i >> 6];
    }
    for (int i = idx; i < N_NODES; i += gridDim.x * blockDim.x) cnt[i] = 0;
}

// ---------------------------------------------------------------------------
// input scatter: bin[in_idx[i]][b] = bias + in_w[i]*x[b][i], last-wins
// ---------------------------------------------------------------------------
__global__ void input_scatter_kernel(float* __restrict__ bin,
                                     const float* __restrict__ x,
                                     const float* __restrict__ in_w,
                                     const int* __restrict__ in_idx,
                                     const float* __restrict__ biases) {
    int i = blockIdx.x;
    int b = threadIdx.x;
    int node = in_idx[i];
    for (int j = i + 1; j < N_IN; j++)
        if (in_idx[j] == node) return;
    bin[node * BATCH + b] = biases[node] + in_w[i] * x[b * N_IN + i];
}

// ---------------------------------------------------------------------------
// COO -> packed ELL {col, weight_bits}
// ---------------------------------------------------------------------------
__global__ void ell_build_kernel(const int* __restrict__ rows,
                                 const int* __restrict__ cols,
                                 const float* __restrict__ rec_w,
                                 int2* __restrict__ ellm, int* __restrict__ cnt) {
    int e = blockIdx.x * blockDim.x + threadIdx.x;
    if (e >= N_EDGES) return;
    int r = rows[e];
    int s = atomicAdd(&cnt[r], 1);
    if (s < CAP) {
        int2 m;
        m.x = cols[e];
        m.y = __float_as_int(rec_w[e]);
        ellm[r * CAP + s] = m;
    }
}

// ---------------------------------------------------------------------------
// shared per-node SpMV+activation body (used by both paths)
// lane = g*16+li ; group g handles edge slots ≡ g (mod 4), pair-unrolled x2.
// OOB slots carry w=0/col=0 so no guards needed in the hot loop.
// ---------------------------------------------------------------------------
__device__ __forceinline__ void node_update(
        int node, int g, int li, int lane,
        int mycol, float myw, int pairs,
        const float4* __restrict__ hi, float4* __restrict__ ho,
        const float4* __restrict__ binf4) {
    float ax = 0.f, ay = 0.f, az = 0.f, aw = 0.f;
    float bx = 0.f, by = 0.f, bz = 0.f, bw = 0.f;
    for (int s = 0; s < pairs; s++) {
        int   s0 = (s << 3) | g;          // slot s*8 + g
        int   c0 = __shfl(mycol, s0);
        float w0 = __shfl(myw,  s0);
        int   c1 = __shfl(mycol, s0 + 4); // slot s*8 + 4 + g
        float w1 = __shfl(myw,  s0 + 4);
        float4 v0 = hi[c0 * 16 + li];
        float4 v1 = hi[c1 * 16 + li];
        ax += w0 * v0.x; ay += w0 * v0.y; az += w0 * v0.z; aw += w0 * v0.w;
        bx += w1 * v1.x; by += w1 * v1.y; bz += w1 * v1.z; bw += w1 * v1.w;
    }
    ax += bx; ay += by; az += bz; aw += bw;
    // cross-group reduction over lanes {li, li+16, li+32, li+48}
    ax += __shfl_xor(ax, 16); ay += __shfl_xor(ay, 16);
    az += __shfl_xor(az, 16); aw += __shfl_xor(aw, 16);
    ax += __shfl_xor(ax, 32); ay += __shfl_xor(ay, 32);
    az += __shfl_xor(az, 32); aw += __shfl_xor(aw, 32);

    if (g == 0) {
        float4 bias = binf4[node * 16 + li];
        float rx = bias.x + ax, ry = bias.y + ay;
        float rz = bias.z + az, rw = bias.w + aw;
        float ux = (rx < 0.f) ? rx * LEAK : rx;
        float uy = (ry < 0.f) ? ry * LEAK : ry;
        float uz = (rz < 0.f) ? rz * LEAK : rz;
        float uw = (rw < 0.f) ? rw * LEAK : rw;
        float4 r;
        r.x = (ux > 0.5f) ? (1.0f - 0.25f / ux) : ux;
        r.y = (uy > 0.5f) ? (1.0f - 0.25f / uy) : uy;
        r.z = (uz > 0.5f) ? (1.0f - 0.25f / uz) : uz;
        r.w = (uw > 0.5f) ? (1.0f - 0.25f / uw) : uw;
        ho[node * 16 + li] = r;
    }
}

// ---------------------------------------------------------------------------
// persistent cooperative kernel: all 150 iterations, metadata register-cached
// ---------------------------------------------------------------------------
__global__ __launch_bounds__(NTHREADS, 4) void recurrent_persistent(
        float* __restrict__ h0, float* __restrict__ h1,
        const float* __restrict__ bin,
        const int2* __restrict__ ellm, const int* __restrict__ cnt) {
    cg::grid_group grid = cg::this_grid();

    int wave = (blockIdx.x << 2) | (threadIdx.x >> 6);
    int lane = threadIdx.x & 63;
    int g    = lane >> 4;
    int li   = lane & 15;

    int   mycol[NPW];
    float myw[NPW];
    int   pairs[NPW];

#pragma unroll
    for (int j = 0; j < NPW; j++) {
        int node = wave + j * NWAVES;
        mycol[j] = 0; myw[j] = 0.0f; pairs[j] = 0;
        if (node < N_NODES) {
            int c = cnt[node];
            if (c > CAP) c = CAP;
            pairs[j] = (c + 7) >> 3;
            if (lane < c) {
                int2 m = ellm[node * CAP + lane];
                mycol[j] = m.x;
                myw[j]   = __int_as_float(m.y);
            }
        }
    }

    const float4* binf4 = (const float4*)bin;
    for (int t = 0; t < ITERS; t++) {
        const float4* hi = (const float4*)((t & 1) ? h1 : h0);
        float4*       ho = (float4*)((t & 1) ? h0 : h1);
#pragma unroll
        for (int j = 0; j < NPW; j++) {
            int node = wave + j * NWAVES;
            if (node < N_NODES)
                node_update(node, g, li, lane, mycol[j], myw[j], pairs[j],
                            hi, ho, binf4);
        }
        grid.sync();
    }
}

// ---------------------------------------------------------------------------
// fallback: one iteration per launch (non-persistent), one node per wave
// ---------------------------------------------------------------------------
__global__ __launch_bounds__(256) void step_kernel(
        const float* __restrict__ h_in, float* __restrict__ h_out,
        const float* __restrict__ bin,
        const int2* __restrict__ ellm, const int* __restrict__ cnt) {
    int node = blockIdx.x * 4 + (threadIdx.x >> 6);
    if (node >= N_NODES) return;
    int lane = threadIdx.x & 63;
    int g    = lane >> 4;
    int li   = lane & 15;

    int c = cnt[node];
    if (c > CAP) c = CAP;
    int   mycol = 0;
    float myw   = 0.0f;
    if (lane < c) {
        int2 m = ellm[node * CAP + lane];
        mycol = m.x;
        myw   = __int_as_float(m.y);
    }
    node_update(node, g, li, lane, mycol, myw, (c + 7) >> 3,
                (const float4*)h_in, (float4*)h_out, (const float4*)bin);
}

// ---------------------------------------------------------------------------
// output gather: out[b][o] = out_w[o] * h[out_idx[o]][b]
// ---------------------------------------------------------------------------
__global__ void output_kernel(const float* __restrict__ h,
                              const int* __restrict__ out_idx,
                              const float* __restrict__ out_w,
                              float* __restrict__ out) {
    int o = threadIdx.x;
    int b = blockIdx.x;
    out[b * N_OUT + o] = out_w[o] * h[out_idx[o] * BATCH + b];
}

// ---------------------------------------------------------------------------
extern "C" void kernel_launch(void* const* d_in, const int* in_sizes, int n_in,
                              void* d_out, int out_size, void* d_ws, size_t ws_size,
                              hipStream_t stream) {
    const float* x      = (const float*)d_in[0];
    const float* in_w   = (const float*)d_in[1];
    const float* out_w  = (const float*)d_in[2];
    const float* rec_w  = (const float*)d_in[3];
    const float* biases = (const float*)d_in[4];
    const int*   rows   = (const int*)d_in[5];
    const int*   cols   = (const int*)d_in[6];
    const int*   in_idx = (const int*)d_in[7];
    const int*   oidx   = (const int*)d_in[8];
    float* out = (float*)d_out;

    char* ws = (char*)d_ws;
    float* h0   = (float*)ws;   ws += (size_t)N_NODES * BATCH * 4;
    float* h1   = (float*)ws;   ws += (size_t)N_NODES * BATCH * 4;
    float* bin  = (float*)ws;   ws += (size_t)N_NODES * BATCH * 4;
    int2*  ellm = (int2*)ws;    ws += (size_t)N_NODES * CAP * 8;
    int*   cnt  = (int*)ws;     ws += (size_t)N_NODES * 4;

    init_kernel<<<1024, 256, 0, stream>>>(h0, bin, cnt, biases);
    input_scatter_kernel<<<N_IN, BATCH, 0, stream>>>(bin, x, in_w, in_idx, biases);
    ell_build_kernel<<<(N_EDGES + 255) / 256, 256, 0, stream>>>(rows, cols, rec_w,
                                                                ellm, cnt);

    void* args[] = { (void*)&h0, (void*)&h1, (void*)&bin, (void*)&ellm, (void*)&cnt };
    hipError_t ce = hipLaunchCooperativeKernel((void*)recurrent_persistent,
                                               dim3(NBLOCKS), dim3(NTHREADS),
                                               args, 0, stream);
    if (ce != hipSuccess) {
        // fallback: 150 explicit launches, same ping-pong parity (final in h0)
        float* hA = h0;
        float* hB = h1;
        for (int t = 0; t < ITERS; t++) {
            step_kernel<<<N_NODES / 4, 256, 0, stream>>>(hA, hB, bin, ellm, cnt);
            float* tmp = hA; hA = hB; hB = tmp;
        }
    }

    // ITERS even -> final state in h0 on both paths
    output_kernel<<<BATCH, N_OUT, 0, stream>>>(h0, oidx, out_w, out);
}

// Round 4
// 2217.583 us; speedup vs baseline: 8.4992x; 8.4992x over previous
//
#include <hip/hip_runtime.h>
#include <hip/hip_bf16.h>

#define N_NODES 20000
#define N_EDGES 320000
#define BATCH   64
#define N_IN    128
#define N_OUT   256
#define CAP     64
#define ITERS   150
#define LEAK    0.01f

// ---------------------------------------------------------------------------
// init: h0 = 0, bin = bias broadcast, cnt = 0
// ---------------------------------------------------------------------------
__global__ void init_kernel(float* __restrict__ h0, float* __restrict__ bin,
                            int* __restrict__ cnt, const float* __restrict__ biases) {
    int idx = blockIdx.x * blockDim.x + threadIdx.x;
    int total = N_NODES * BATCH;
    for (int i = idx; i < total; i += gridDim.x * blockDim.x) {
        h0[i]  = 0.0f;
        bin[i] = biases[i >> 6];
    }
    for (int i = idx; i < N_NODES; i += gridDim.x * blockDim.x) cnt[i] = 0;
}

// ---------------------------------------------------------------------------
// input scatter: bin[in_idx[i]][b] = bias + in_w[i]*x[b][i], last-wins
// ---------------------------------------------------------------------------
__global__ void input_scatter_kernel(float* __restrict__ bin,
                                     const float* __restrict__ x,
                                     const float* __restrict__ in_w,
                                     const int* __restrict__ in_idx,
                                     const float* __restrict__ biases) {
    int i = blockIdx.x;
    int b = threadIdx.x;
    int node = in_idx[i];
    for (int j = i + 1; j < N_IN; j++)
        if (in_idx[j] == node) return;
    bin[node * BATCH + b] = biases[node] + in_w[i] * x[b * N_IN + i];
}

// ---------------------------------------------------------------------------
// COO -> packed ELL {col, weight_bits}; unfilled slots stay (0, 0.0f) from
// the pre-zero pass so the hot loop needs no guards.
// ---------------------------------------------------------------------------
__global__ void ell_zero_kernel(int2* __restrict__ ellm) {
    int i = blockIdx.x * blockDim.x + threadIdx.x;
    int total = N_NODES * CAP;
    for (; i < total; i += gridDim.x * blockDim.x) ellm[i] = make_int2(0, 0);
}

__global__ void ell_build_kernel(const int* __restrict__ rows,
                                 const int* __restrict__ cols,
                                 const float* __restrict__ rec_w,
                                 int2* __restrict__ ellm, int* __restrict__ cnt) {
    int e = blockIdx.x * blockDim.x + threadIdx.x;
    if (e >= N_EDGES) return;
    int r = rows[e];
    int s = atomicAdd(&cnt[r], 1);
    if (s < CAP) {
        int2 m;
        m.x = cols[e];
        m.y = __float_as_int(rec_w[e]);
        ellm[r * CAP + s] = m;
    }
}

// ---------------------------------------------------------------------------
// step kernel: one wave = one (node, batch-half) task.
//   half = blockIdx & 1  ->  with blockIdx%8 = XCD round-robin, even XCDs
//   always process half 0, odd XCDs half 1: per-XCD h working set = 2.56 MB,
//   fits the 4 MB per-XCD L2 (vs 5.1 MB thrash without the split).
// Lane = g*8+li: group g (0..7) handles edge slots == g (mod 8), li indexes
// the half-row as float4 (8 lanes x 16B = 128B coalesced gather per edge).
// 4-slot unroll: 4 independent gathers in flight per lane; zero-padded slots
// (w=0, col=0) make the loop guard-free; c<=32 (virtually all nodes) = 1 pass.
// ---------------------------------------------------------------------------
__global__ __launch_bounds__(256) void step_kernel(
        const float* __restrict__ h_in, float* __restrict__ h_out,
        const float* __restrict__ bin,
        const int2* __restrict__ ellm, const int* __restrict__ cnt) {
    int wave = threadIdx.x >> 6;
    int lane = threadIdx.x & 63;
    int half = blockIdx.x & 1;
    int node = (blockIdx.x >> 1) * 4 + wave;
    if (node >= N_NODES) return;

    int g  = lane >> 3;          // edge-slot group 0..7
    int li = lane & 7;           // float4 index within the 32-wide half
    int off = half * 8 + li;     // float4 offset within a 64-wide node row

    int c = cnt[node];
    if (c > CAP) c = CAP;

    int   mycol = 0;
    float myw   = 0.0f;
    if (lane < c) {
        int2 m = ellm[node * CAP + lane];
        mycol = m.x;
        myw   = __int_as_float(m.y);
    }

    const float4* hi = (const float4*)h_in;
    int passes = (c + 31) >> 5;

    float4 a0 = make_float4(0.f, 0.f, 0.f, 0.f);
    float4 a1 = make_float4(0.f, 0.f, 0.f, 0.f);
    float4 a2 = make_float4(0.f, 0.f, 0.f, 0.f);
    float4 a3 = make_float4(0.f, 0.f, 0.f, 0.f);

    for (int s = 0; s < passes; s++) {
        int base = (s << 5) + g;
        int   c0 = __shfl(mycol, base);      float w0 = __shfl(myw, base);
        int   c1 = __shfl(mycol, base + 8);  float w1 = __shfl(myw, base + 8);
        int   c2 = __shfl(mycol, base + 16); float w2 = __shfl(myw, base + 16);
        int   c3 = __shfl(mycol, base + 24); float w3 = __shfl(myw, base + 24);
        float4 v0 = hi[(c0 << 4) + off];
        float4 v1 = hi[(c1 << 4) + off];
        float4 v2 = hi[(c2 << 4) + off];
        float4 v3 = hi[(c3 << 4) + off];
        a0.x += w0 * v0.x; a0.y += w0 * v0.y; a0.z += w0 * v0.z; a0.w += w0 * v0.w;
        a1.x += w1 * v1.x; a1.y += w1 * v1.y; a1.z += w1 * v1.z; a1.w += w1 * v1.w;
        a2.x += w2 * v2.x; a2.y += w2 * v2.y; a2.z += w2 * v2.z; a2.w += w2 * v2.w;
        a3.x += w3 * v3.x; a3.y += w3 * v3.y; a3.z += w3 * v3.z; a3.w += w3 * v3.w;
    }
    float ax = (a0.x + a1.x) + (a2.x + a3.x);
    float ay = (a0.y + a1.y) + (a2.y + a3.y);
    float az = (a0.z + a1.z) + (a2.z + a3.z);
    float aw = (a0.w + a1.w) + (a2.w + a3.w);

    // reduce across the 8 groups (lanes li, li+8, ..., li+56)
    ax += __shfl_xor(ax, 8);  ay += __shfl_xor(ay, 8);
    az += __shfl_xor(az, 8);  aw += __shfl_xor(aw, 8);
    ax += __shfl_xor(ax, 16); ay += __shfl_xor(ay, 16);
    az += __shfl_xor(az, 16); aw += __shfl_xor(aw, 16);
    ax += __shfl_xor(ax, 32); ay += __shfl_xor(ay, 32);
    az += __shfl_xor(az, 32); aw += __shfl_xor(aw, 32);

    if (g == 0) {
        float4 bias = ((const float4*)bin)[(node << 4) + off];
        float rx = bias.x + ax, ry = bias.y + ay;
        float rz = bias.z + az, rw = bias.w + aw;
        float ux = (rx < 0.f) ? rx * LEAK : rx;
        float uy = (ry < 0.f) ? ry * LEAK : ry;
        float uz = (rz < 0.f) ? rz * LEAK : rz;
        float uw = (rw < 0.f) ? rw * LEAK : rw;
        float4 r;
        r.x = (ux > 0.5f) ? (1.0f - 0.25f / ux) : ux;
        r.y = (uy > 0.5f) ? (1.0f - 0.25f / uy) : uy;
        r.z = (uz > 0.5f) ? (1.0f - 0.25f / uz) : uz;
        r.w = (uw > 0.5f) ? (1.0f - 0.25f / uw) : uw;
        ((float4*)h_out)[(node << 4) + off] = r;
    }
}

// ---------------------------------------------------------------------------
// output gather: out[b][o] = out_w[o] * h[out_idx[o]][b]
// ---------------------------------------------------------------------------
__global__ void output_kernel(const float* __restrict__ h,
                              const int* __restrict__ out_idx,
                              const float* __restrict__ out_w,
                              float* __restrict__ out) {
    int o = threadIdx.x;
    int b = blockIdx.x;
    out[b * N_OUT + o] = out_w[o] * h[out_idx[o] * BATCH + b];
}

// ---------------------------------------------------------------------------
extern "C" void kernel_launch(void* const* d_in, const int* in_sizes, int n_in,
                              void* d_out, int out_size, void* d_ws, size_t ws_size,
                              hipStream_t stream) {
    const float* x      = (const float*)d_in[0];
    const float* in_w   = (const float*)d_in[1];
    const float* out_w  = (const float*)d_in[2];
    const float* rec_w  = (const float*)d_in[3];
    const float* biases = (const float*)d_in[4];
    const int*   rows   = (const int*)d_in[5];
    const int*   cols   = (const int*)d_in[6];
    const int*   in_idx = (const int*)d_in[7];
    const int*   oidx   = (const int*)d_in[8];
    float* out = (float*)d_out;

    char* ws = (char*)d_ws;
    float* h0   = (float*)ws;   ws += (size_t)N_NODES * BATCH * 4;
    float* h1   = (float*)ws;   ws += (size_t)N_NODES * BATCH * 4;
    float* bin  = (float*)ws;   ws += (size_t)N_NODES * BATCH * 4;
    int2*  ellm = (int2*)ws;    ws += (size_t)N_NODES * CAP * 8;
    int*   cnt  = (int*)ws;     ws += (size_t)N_NODES * 4;

    init_kernel<<<1024, 256, 0, stream>>>(h0, bin, cnt, biases);
    input_scatter_kernel<<<N_IN, BATCH, 0, stream>>>(bin, x, in_w, in_idx, biases);
    ell_zero_kernel<<<1024, 256, 0, stream>>>(ellm);
    ell_build_kernel<<<(N_EDGES + 255) / 256, 256, 0, stream>>>(rows, cols, rec_w,
                                                                ellm, cnt);

    // 150 iterations; grid = 2 batch-halves x 5000 node-blocks
    float* hA = h0;
    float* hB = h1;
    for (int t = 0; t < ITERS; t++) {
        step_kernel<<<(N_NODES / 4) * 2, 256, 0, stream>>>(hA, hB, bin, ellm, cnt);
        float* tmp = hA; hA = hB; hB = tmp;
    }

    // ITERS even -> final state in h0
    output_kernel<<<BATCH, N_OUT, 0, stream>>>(h0, oidx, out_w, out);
}

// Round 5
// 2151.576 us; speedup vs baseline: 8.7600x; 1.0307x over previous
//
#include <hip/hip_runtime.h>
#include <hip/hip_bf16.h>

#define N_NODES 20000
#define N_EDGES 320000
#define BATCH   64
#define N_IN    128
#define N_OUT   256
#define CAP     64
#define ITERS   150
#define LEAK    0.01f

// ---------------------------------------------------------------------------
// init: h0 = 0, bin = bias broadcast, cnt = 0
// ---------------------------------------------------------------------------
__global__ void init_kernel(float* __restrict__ h0, float* __restrict__ bin,
                            int* __restrict__ cnt, const float* __restrict__ biases) {
    int idx = blockIdx.x * blockDim.x + threadIdx.x;
    int total = N_NODES * BATCH;
    for (int i = idx; i < total; i += gridDim.x * blockDim.x) {
        h0[i]  = 0.0f;
        bin[i] = biases[i >> 6];
    }
    for (int i = idx; i < N_NODES; i += gridDim.x * blockDim.x) cnt[i] = 0;
}

// ---------------------------------------------------------------------------
// input scatter: bin[in_idx[i]][b] = bias + in_w[i]*x[b][i], last-wins
// ---------------------------------------------------------------------------
__global__ void input_scatter_kernel(float* __restrict__ bin,
                                     const float* __restrict__ x,
                                     const float* __restrict__ in_w,
                                     const int* __restrict__ in_idx,
                                     const float* __restrict__ biases) {
    int i = blockIdx.x;
    int b = threadIdx.x;
    int node = in_idx[i];
    for (int j = i + 1; j < N_IN; j++)
        if (in_idx[j] == node) return;
    bin[node * BATCH + b] = biases[node] + in_w[i] * x[b * N_IN + i];
}

// ---------------------------------------------------------------------------
// COO -> packed ELL {col, weight_bits}; zero-padded slots are harmless in the
// hot loop (col 0, w = 0).
// ---------------------------------------------------------------------------
__global__ void ell_zero_kernel(int2* __restrict__ ellm) {
    int i = blockIdx.x * blockDim.x + threadIdx.x;
    int total = N_NODES * CAP;
    for (; i < total; i += gridDim.x * blockDim.x) ellm[i] = make_int2(0, 0);
}

__global__ void ell_build_kernel(const int* __restrict__ rows,
                                 const int* __restrict__ cols,
                                 const float* __restrict__ rec_w,
                                 int2* __restrict__ ellm, int* __restrict__ cnt) {
    int e = blockIdx.x * blockDim.x + threadIdx.x;
    if (e >= N_EDGES) return;
    int r = rows[e];
    int s = atomicAdd(&cnt[r], 1);
    if (s < CAP) {
        int2 m;
        m.x = cols[e];
        m.y = __float_as_int(rec_w[e]);
        ellm[r * CAP + s] = m;
    }
}

// ---------------------------------------------------------------------------
// step kernel: one wave per node, lane = batch element.
// node is forced uniform via readfirstlane so cnt/metadata loads become SMEM
// (s_load), weights ride in SGPRs (v_fmac v,s,v), gather addresses are
// SALU-computed (global_load_dword v, v_lane, s[base]).  Per edge: 1 VALU op.
// No cross-lane reduction: each lane owns batch element `lane` end-to-end.
// 4 independent accumulators give 4 gathers in flight (MLP).
// ---------------------------------------------------------------------------
__global__ __launch_bounds__(256) void step_kernel(
        const float* __restrict__ h_in, float* __restrict__ h_out,
        const float* __restrict__ bin,
        const int4* __restrict__ ellm4, const int* __restrict__ cnt) {
    int lane = threadIdx.x & 63;
    int node = __builtin_amdgcn_readfirstlane((blockIdx.x << 2) | (threadIdx.x >> 6));

    int c = cnt[node];
    if (c > CAP) c = CAP;
    int iters = (c + 3) >> 2;

    // 2 slots per int4: slot 2i -> (x=col, y=w_bits), slot 2i+1 -> (z, w)
    const int4* mp = ellm4 + node * (CAP / 2);

    float a0 = 0.f, a1 = 0.f, a2 = 0.f, a3 = 0.f;
    for (int i = 0; i < iters; i++) {
        int4 pa = mp[2 * i];
        int4 pb = mp[2 * i + 1];
        const float* h0p = h_in + ((size_t)pa.x << 6);
        const float* h1p = h_in + ((size_t)pa.z << 6);
        const float* h2p = h_in + ((size_t)pb.x << 6);
        const float* h3p = h_in + ((size_t)pb.z << 6);
        float w0 = __int_as_float(pa.y);
        float w1 = __int_as_float(pa.w);
        float w2 = __int_as_float(pb.y);
        float w3 = __int_as_float(pb.w);
        a0 = fmaf(w0, h0p[lane], a0);
        a1 = fmaf(w1, h1p[lane], a1);
        a2 = fmaf(w2, h2p[lane], a2);
        a3 = fmaf(w3, h3p[lane], a3);
    }
    float acc = (a0 + a1) + (a2 + a3);

    float r = bin[(node << 6) + lane] + acc;
    float u = (r < 0.f) ? r * LEAK : r;
    h_out[(node << 6) + lane] = (u > 0.5f) ? (1.0f - 0.25f / u) : u;
}

// ---------------------------------------------------------------------------
// output gather: out[b][o] = out_w[o] * h[out_idx[o]][b]
// ---------------------------------------------------------------------------
__global__ void output_kernel(const float* __restrict__ h,
                              const int* __restrict__ out_idx,
                              const float* __restrict__ out_w,
                              float* __restrict__ out) {
    int o = threadIdx.x;
    int b = blockIdx.x;
    out[b * N_OUT + o] = out_w[o] * h[out_idx[o] * BATCH + b];
}

// ---------------------------------------------------------------------------
extern "C" void kernel_launch(void* const* d_in, const int* in_sizes, int n_in,
                              void* d_out, int out_size, void* d_ws, size_t ws_size,
                              hipStream_t stream) {
    const float* x      = (const float*)d_in[0];
    const float* in_w   = (const float*)d_in[1];
    const float* out_w  = (const float*)d_in[2];
    const float* rec_w  = (const float*)d_in[3];
    const float* biases = (const float*)d_in[4];
    const int*   rows   = (const int*)d_in[5];
    const int*   cols   = (const int*)d_in[6];
    const int*   in_idx = (const int*)d_in[7];
    const int*   oidx   = (const int*)d_in[8];
    float* out = (float*)d_out;

    char* ws = (char*)d_ws;
    float* h0   = (float*)ws;   ws += (size_t)N_NODES * BATCH * 4;
    float* h1   = (float*)ws;   ws += (size_t)N_NODES * BATCH * 4;
    float* bin  = (float*)ws;   ws += (size_t)N_NODES * BATCH * 4;
    int2*  ellm = (int2*)ws;    ws += (size_t)N_NODES * CAP * 8;
    int*   cnt  = (int*)ws;     ws += (size_t)N_NODES * 4;

    init_kernel<<<1024, 256, 0, stream>>>(h0, bin, cnt, biases);
    input_scatter_kernel<<<N_IN, BATCH, 0, stream>>>(bin, x, in_w, in_idx, biases);
    ell_zero_kernel<<<1024, 256, 0, stream>>>(ellm);
    ell_build_kernel<<<(N_EDGES + 255) / 256, 256, 0, stream>>>(rows, cols, rec_w,
                                                                ellm, cnt);

    // 150 iterations; one wave per node, 4 nodes per block -> exact grid
    float* hA = h0;
    float* hB = h1;
    for (int t = 0; t < ITERS; t++) {
        step_kernel<<<N_NODES / 4, 256, 0, stream>>>(hA, hB, bin,
                                                     (const int4*)ellm, cnt);
        float* tmp = hA; hA = hB; hB = tmp;
    }

    // ITERS even -> final state in h0
    output_kernel<<<BATCH, N_OUT, 0, stream>>>(h0, oidx, out_w, out);
}

// Round 6
// 1609.349 us; speedup vs baseline: 11.7114x; 1.3369x over previous
//
#include <hip/hip_runtime.h>
#include <hip/hip_fp16.h>

#define N_NODES 20000
#define N_EDGES 320000
#define BATCH   64
#define N_IN    128
#define N_OUT   256
#define CAP     64
#define ITERS   150
#define LEAK    0.01f

// ---------------------------------------------------------------------------
// init: h0 = 0 (fp16), bin = bias broadcast (fp32), cnt = 0
// ---------------------------------------------------------------------------
__global__ void init_kernel(__half* __restrict__ h0, float* __restrict__ bin,
                            int* __restrict__ cnt, const float* __restrict__ biases) {
    int idx = blockIdx.x * blockDim.x + threadIdx.x;
    int total = N_NODES * BATCH;
    for (int i = idx; i < total; i += gridDim.x * blockDim.x) {
        h0[i]  = __float2half(0.0f);
        bin[i] = biases[i >> 6];
    }
    for (int i = idx; i < N_NODES; i += gridDim.x * blockDim.x) cnt[i] = 0;
}

// ---------------------------------------------------------------------------
// input scatter: bin[in_idx[i]][b] = bias + in_w[i]*x[b][i], last-wins
// ---------------------------------------------------------------------------
__global__ void input_scatter_kernel(float* __restrict__ bin,
                                     const float* __restrict__ x,
                                     const float* __restrict__ in_w,
                                     const int* __restrict__ in_idx,
                                     const float* __restrict__ biases) {
    int i = blockIdx.x;
    int b = threadIdx.x;
    int node = in_idx[i];
    for (int j = i + 1; j < N_IN; j++)
        if (in_idx[j] == node) return;
    bin[node * BATCH + b] = biases[node] + in_w[i] * x[b * N_IN + i];
}

// ---------------------------------------------------------------------------
// COO -> packed ELL {col, w_fp32_bits}; padded slots stay (0, 0.0f): harmless
// guard-free gathers of row 0 with weight 0.
// ---------------------------------------------------------------------------
__global__ void ell_zero_kernel(int2* __restrict__ ellm) {
    int i = blockIdx.x * blockDim.x + threadIdx.x;
    int total = N_NODES * CAP;
    for (; i < total; i += gridDim.x * blockDim.x) ellm[i] = make_int2(0, 0);
}

__global__ void ell_build_kernel(const int* __restrict__ rows,
                                 const int* __restrict__ cols,
                                 const float* __restrict__ rec_w,
                                 int2* __restrict__ ellm, int* __restrict__ cnt) {
    int e = blockIdx.x * blockDim.x + threadIdx.x;
    if (e >= N_EDGES) return;
    int r = rows[e];
    int s = atomicAdd(&cnt[r], 1);
    if (s < CAP) {
        int2 m;
        m.x = cols[e];
        m.y = __float_as_int(rec_w[e]);
        ellm[r * CAP + s] = m;
    }
}

// ---------------------------------------------------------------------------
// step kernel: one wave per node, lane = batch element.
// h stored fp16 [node][64] -> one edge gather = 128B coalesced; full h state
// is 2.56 MB and fits each XCD's 4MB L2 (no per-step thrash).
// node forced wave-uniform (readfirstlane) so metadata rides the scalar pipe;
// weights stay fp32 in SGPRs; accumulate fp32; 8 gathers in flight.
// ---------------------------------------------------------------------------
__global__ __launch_bounds__(256) void step_kernel(
        const __half* __restrict__ h_in, __half* __restrict__ h_out,
        const float* __restrict__ bin,
        const int4* __restrict__ ellm4, const int* __restrict__ cnt) {
    int lane = threadIdx.x & 63;
    int node = __builtin_amdgcn_readfirstlane((blockIdx.x << 2) | (threadIdx.x >> 6));

    int c = cnt[node];
    if (c > CAP) c = CAP;
    int iters = (c + 7) >> 3;

    // 2 slots per int4: (x=col0, y=w0_bits, z=col1, w=w1_bits)
    const int4* mp = ellm4 + node * (CAP / 2);

    float a0 = 0.f, a1 = 0.f, a2 = 0.f, a3 = 0.f;
    float a4 = 0.f, a5 = 0.f, a6 = 0.f, a7 = 0.f;
    for (int i = 0; i < iters; i++) {
        int4 pa = mp[4 * i];
        int4 pb = mp[4 * i + 1];
        int4 pc = mp[4 * i + 2];
        int4 pd = mp[4 * i + 3];
        const __half* p0 = h_in + ((size_t)pa.x << 6);
        const __half* p1 = h_in + ((size_t)pa.z << 6);
        const __half* p2 = h_in + ((size_t)pb.x << 6);
        const __half* p3 = h_in + ((size_t)pb.z << 6);
        const __half* p4 = h_in + ((size_t)pc.x << 6);
        const __half* p5 = h_in + ((size_t)pc.z << 6);
        const __half* p6 = h_in + ((size_t)pd.x << 6);
        const __half* p7 = h_in + ((size_t)pd.z << 6);
        a0 = fmaf(__int_as_float(pa.y), __half2float(p0[lane]), a0);
        a1 = fmaf(__int_as_float(pa.w), __half2float(p1[lane]), a1);
        a2 = fmaf(__int_as_float(pb.y), __half2float(p2[lane]), a2);
        a3 = fmaf(__int_as_float(pb.w), __half2float(p3[lane]), a3);
        a4 = fmaf(__int_as_float(pc.y), __half2float(p4[lane]), a4);
        a5 = fmaf(__int_as_float(pc.w), __half2float(p5[lane]), a5);
        a6 = fmaf(__int_as_float(pd.y), __half2float(p6[lane]), a6);
        a7 = fmaf(__int_as_float(pd.w), __half2float(p7[lane]), a7);
    }
    float acc = ((a0 + a1) + (a2 + a3)) + ((a4 + a5) + (a6 + a7));

    float r = bin[(node << 6) + lane] + acc;
    float u = (r < 0.f) ? r * LEAK : r;
    float v = (u > 0.5f) ? (1.0f - 0.25f / u) : u;
    h_out[(node << 6) + lane] = __float2half(v);
}

// ---------------------------------------------------------------------------
// output gather: out[b][o] = out_w[o] * h[out_idx[o]][b]
// ---------------------------------------------------------------------------
__global__ void output_kernel(const __half* __restrict__ h,
                              const int* __restrict__ out_idx,
                              const float* __restrict__ out_w,
                              float* __restrict__ out) {
    int o = threadIdx.x;
    int b = blockIdx.x;
    out[b * N_OUT + o] = out_w[o] * __half2float(h[out_idx[o] * BATCH + b]);
}

// ---------------------------------------------------------------------------
extern "C" void kernel_launch(void* const* d_in, const int* in_sizes, int n_in,
                              void* d_out, int out_size, void* d_ws, size_t ws_size,
                              hipStream_t stream) {
    const float* x      = (const float*)d_in[0];
    const float* in_w   = (const float*)d_in[1];
    const float* out_w  = (const float*)d_in[2];
    const float* rec_w  = (const float*)d_in[3];
    const float* biases = (const float*)d_in[4];
    const int*   rows   = (const int*)d_in[5];
    const int*   cols   = (const int*)d_in[6];
    const int*   in_idx = (const int*)d_in[7];
    const int*   oidx   = (const int*)d_in[8];
    float* out = (float*)d_out;

    char* ws = (char*)d_ws;
    __half* h0  = (__half*)ws;  ws += (size_t)N_NODES * BATCH * 2;   // 2.56 MB
    __half* h1  = (__half*)ws;  ws += (size_t)N_NODES * BATCH * 2;   // 2.56 MB
    float* bin  = (float*)ws;   ws += (size_t)N_NODES * BATCH * 4;   // 5.12 MB
    int2*  ellm = (int2*)ws;    ws += (size_t)N_NODES * CAP * 8;     // 10.24 MB
    int*   cnt  = (int*)ws;     ws += (size_t)N_NODES * 4;

    init_kernel<<<1024, 256, 0, stream>>>(h0, bin, cnt, biases);
    input_scatter_kernel<<<N_IN, BATCH, 0, stream>>>(bin, x, in_w, in_idx, biases);
    ell_zero_kernel<<<1024, 256, 0, stream>>>(ellm);
    ell_build_kernel<<<(N_EDGES + 255) / 256, 256, 0, stream>>>(rows, cols, rec_w,
                                                                ellm, cnt);

    // 150 iterations; one wave per node, 4 nodes per block
    __half* hA = h0;
    __half* hB = h1;
    for (int t = 0; t < ITERS; t++) {
        step_kernel<<<N_NODES / 4, 256, 0, stream>>>(hA, hB, bin,
                                                     (const int4*)ellm, cnt);
        __half* tmp = hA; hA = hB; hB = tmp;
    }

    // ITERS even -> final state in h0
    output_kernel<<<BATCH, N_OUT, 0, stream>>>(h0, oidx, out_w, out);
}

// Round 7
// 1524.078 us; speedup vs baseline: 12.3666x; 1.0559x over previous
//
#include <hip/hip_runtime.h>
#include <hip/hip_fp16.h>

#define N_NODES 20000
#define N_EDGES 320000
#define BATCH   64
#define N_IN    128
#define N_OUT   256
#define CAP     64
#define ITERS   150
#define LEAK    0.01f

#define CNT_MASK 0x3FFFFFFF
#define FLAG_BIT (1 << 30)

// ---------------------------------------------------------------------------
// init: h0 = 0 (fp16), bin = bias broadcast (fp32), cnt = 0
// ---------------------------------------------------------------------------
__global__ void init_kernel(__half* __restrict__ h0, float* __restrict__ bin,
                            int* __restrict__ cnt, const float* __restrict__ biases) {
    int idx = blockIdx.x * blockDim.x + threadIdx.x;
    int total = N_NODES * BATCH;
    for (int i = idx; i < total; i += gridDim.x * blockDim.x) {
        h0[i]  = __float2half(0.0f);
        bin[i] = biases[i >> 6];
    }
    for (int i = idx; i < N_NODES; i += gridDim.x * blockDim.x) cnt[i] = 0;
}

// ---------------------------------------------------------------------------
// input scatter: bin[in_idx[i]][b] = bias + in_w[i]*x[b][i], last-wins.
// Also tags the node as "has input" (bit 30 of cnt) so the step kernel only
// reads bin rows for these <=128 nodes.
// ---------------------------------------------------------------------------
__global__ void input_scatter_kernel(float* __restrict__ bin,
                                     const float* __restrict__ x,
                                     const float* __restrict__ in_w,
                                     const int* __restrict__ in_idx,
                                     const float* __restrict__ biases,
                                     int* __restrict__ cnt) {
    int i = blockIdx.x;
    int b = threadIdx.x;
    int node = in_idx[i];
    if (b == 0) atomicOr(&cnt[node], FLAG_BIT);   // set even if overwritten later
    for (int j = i + 1; j < N_IN; j++)
        if (in_idx[j] == node) return;
    bin[node * BATCH + b] = biases[node] + in_w[i] * x[b * N_IN + i];
}

// ---------------------------------------------------------------------------
// COO -> permuted ELL {col, w_fp32_bits}. Slot s lands at index
// (s&3)*16 + (s>>2): lane-group g's pass-1 slots (s = 4i+g, i<8) are then
// contiguous, loadable as 4 int4. Padded slots stay (0, 0.0f) = guard-free.
// ---------------------------------------------------------------------------
__global__ void ell_zero_kernel(int2* __restrict__ ellm) {
    int i = blockIdx.x * blockDim.x + threadIdx.x;
    int total = N_NODES * CAP;
    for (; i < total; i += gridDim.x * blockDim.x) ellm[i] = make_int2(0, 0);
}

__global__ void ell_build_kernel(const int* __restrict__ rows,
                                 const int* __restrict__ cols,
                                 const float* __restrict__ rec_w,
                                 int2* __restrict__ ellm, int* __restrict__ cnt) {
    int e = blockIdx.x * blockDim.x + threadIdx.x;
    if (e >= N_EDGES) return;
    int r = rows[e];
    int s = atomicAdd(&cnt[r], 1) & CNT_MASK;     // mask input flag (bit 30)
    if (s < CAP) {
        int idx = ((s & 3) << 4) | (s >> 2);      // permuted slot
        int2 m;
        m.x = cols[e];
        m.y = __float_as_int(rec_w[e]);
        ellm[r * CAP + idx] = m;
    }
}

// ---------------------------------------------------------------------------
// step kernel: one wave per node. Lane = eg*16+li: edge-group eg (0..3)
// handles slots == eg (mod 4); li indexes 4 batch elems (uint2 of 4 fp16).
// Straight-line pass covers 32 slots (8 gathers, all independent); rare
// c>32 tail is a uniform branch. Non-input nodes skip the bin row read.
// ---------------------------------------------------------------------------
#define ACC4(g, w)                                                   \
    a0 = fmaf(w, __half2float(__ushort_as_half((unsigned short)((g).x & 0xFFFF))), a0); \
    a1 = fmaf(w, __half2float(__ushort_as_half((unsigned short)((g).x >> 16))),   a1); \
    a2 = fmaf(w, __half2float(__ushort_as_half((unsigned short)((g).y & 0xFFFF))), a2); \
    a3 = fmaf(w, __half2float(__ushort_as_half((unsigned short)((g).y >> 16))),   a3);

__global__ __launch_bounds__(256) void step_kernel(
        const __half* __restrict__ h_in, __half* __restrict__ h_out,
        const float* __restrict__ bin, const float* __restrict__ biases,
        const int4* __restrict__ ellm4, const int* __restrict__ cnt) {
    int lane = threadIdx.x & 63;
    int node = __builtin_amdgcn_readfirstlane((blockIdx.x << 2) | (threadIdx.x >> 6));
    int eg = lane >> 4;
    int li = lane & 15;

    int cv = cnt[node];
    int c  = cv & CNT_MASK;
    if (c > CAP) c = CAP;

    // group eg's 16 permuted slots start at int2 index node*64 + eg*16
    // = int4 index node*32 + eg*8
    const int4* mp = ellm4 + node * 32 + eg * 8;
    const uint2* hv = (const uint2*)h_in;

    float a0 = 0.f, a1 = 0.f, a2 = 0.f, a3 = 0.f;

    {   // pass 1: slots 0..31 (guard-free; padded slots are w=0 row-0 hits)
        int4 m0 = mp[0], m1 = mp[1], m2 = mp[2], m3 = mp[3];
        uint2 g0 = hv[(m0.x << 4) + li];
        uint2 g1 = hv[(m0.z << 4) + li];
        uint2 g2 = hv[(m1.x << 4) + li];
        uint2 g3 = hv[(m1.z << 4) + li];
        uint2 g4 = hv[(m2.x << 4) + li];
        uint2 g5 = hv[(m2.z << 4) + li];
        uint2 g6 = hv[(m3.x << 4) + li];
        uint2 g7 = hv[(m3.z << 4) + li];
        ACC4(g0, __int_as_float(m0.y)); ACC4(g1, __int_as_float(m0.w));
        ACC4(g2, __int_as_float(m1.y)); ACC4(g3, __int_as_float(m1.w));
        ACC4(g4, __int_as_float(m2.y)); ACC4(g5, __int_as_float(m2.w));
        ACC4(g6, __int_as_float(m3.y)); ACC4(g7, __int_as_float(m3.w));
    }
    if (c > 32) {   // rare tail: slots 32..63 (uniform branch, no divergence)
        int4 m0 = mp[4], m1 = mp[5], m2 = mp[6], m3 = mp[7];
        uint2 g0 = hv[(m0.x << 4) + li];
        uint2 g1 = hv[(m0.z << 4) + li];
        uint2 g2 = hv[(m1.x << 4) + li];
        uint2 g3 = hv[(m1.z << 4) + li];
        uint2 g4 = hv[(m2.x << 4) + li];
        uint2 g5 = hv[(m2.z << 4) + li];
        uint2 g6 = hv[(m3.x << 4) + li];
        uint2 g7 = hv[(m3.z << 4) + li];
        ACC4(g0, __int_as_float(m0.y)); ACC4(g1, __int_as_float(m0.w));
        ACC4(g2, __int_as_float(m1.y)); ACC4(g3, __int_as_float(m1.w));
        ACC4(g4, __int_as_float(m2.y)); ACC4(g5, __int_as_float(m2.w));
        ACC4(g6, __int_as_float(m3.y)); ACC4(g7, __int_as_float(m3.w));
    }

    // reduce across the 4 edge-groups (lanes li, li+16, li+32, li+48)
    a0 += __shfl_xor(a0, 16); a1 += __shfl_xor(a1, 16);
    a2 += __shfl_xor(a2, 16); a3 += __shfl_xor(a3, 16);
    a0 += __shfl_xor(a0, 32); a1 += __shfl_xor(a1, 32);
    a2 += __shfl_xor(a2, 32); a3 += __shfl_xor(a3, 32);

    if (eg == 0) {
        float b0, b1, b2, b3;
        if (cv & FLAG_BIT) {
            float4 bb = ((const float4*)bin)[node * 16 + li];
            b0 = bb.x; b1 = bb.y; b2 = bb.z; b3 = bb.w;
        } else {
            b0 = b1 = b2 = b3 = biases[node];   // scalar, L2-hot
        }
        float r0 = b0 + a0, r1 = b1 + a1, r2 = b2 + a2, r3 = b3 + a3;
        float u0 = (r0 < 0.f) ? r0 * LEAK : r0;
        float u1 = (r1 < 0.f) ? r1 * LEAK : r1;
        float u2 = (r2 < 0.f) ? r2 * LEAK : r2;
        float u3 = (r3 < 0.f) ? r3 * LEAK : r3;
        float v0 = (u0 > 0.5f) ? (1.0f - 0.25f / u0) : u0;
        float v1 = (u1 > 0.5f) ? (1.0f - 0.25f / u1) : u1;
        float v2 = (u2 > 0.5f) ? (1.0f - 0.25f / u2) : u2;
        float v3 = (u3 > 0.5f) ? (1.0f - 0.25f / u3) : u3;
        union { __half2 h; unsigned u; } p01, p23;
        p01.h = __halves2half2(__float2half(v0), __float2half(v1));
        p23.h = __halves2half2(__float2half(v2), __float2half(v3));
        uint2 st; st.x = p01.u; st.y = p23.u;
        ((uint2*)h_out)[node * 16 + li] = st;
    }
}

// ---------------------------------------------------------------------------
// output gather: out[b][o] = out_w[o] * h[out_idx[o]][b]
// ---------------------------------------------------------------------------
__global__ void output_kernel(const __half* __restrict__ h,
                              const int* __restrict__ out_idx,
                              const float* __restrict__ out_w,
                              float* __restrict__ out) {
    int o = threadIdx.x;
    int b = blockIdx.x;
    out[b * N_OUT + o] = out_w[o] * __half2float(h[out_idx[o] * BATCH + b]);
}

// ---------------------------------------------------------------------------
extern "C" void kernel_launch(void* const* d_in, const int* in_sizes, int n_in,
                              void* d_out, int out_size, void* d_ws, size_t ws_size,
                              hipStream_t stream) {
    const float* x      = (const float*)d_in[0];
    const float* in_w   = (const float*)d_in[1];
    const float* out_w  = (const float*)d_in[2];
    const float* rec_w  = (const float*)d_in[3];
    const float* biases = (const float*)d_in[4];
    const int*   rows   = (const int*)d_in[5];
    const int*   cols   = (const int*)d_in[6];
    const int*   in_idx = (const int*)d_in[7];
    const int*   oidx   = (const int*)d_in[8];
    float* out = (float*)d_out;

    char* ws = (char*)d_ws;
    __half* h0  = (__half*)ws;  ws += (size_t)N_NODES * BATCH * 2;   // 2.56 MB
    __half* h1  = (__half*)ws;  ws += (size_t)N_NODES * BATCH * 2;   // 2.56 MB
    float* bin  = (float*)ws;   ws += (size_t)N_NODES * BATCH * 4;   // 5.12 MB
    int2*  ellm = (int2*)ws;    ws += (size_t)N_NODES * CAP * 8;     // 10.24 MB
    int*   cnt  = (int*)ws;     ws += (size_t)N_NODES * 4;

    init_kernel<<<1024, 256, 0, stream>>>(h0, bin, cnt, biases);
    input_scatter_kernel<<<N_IN, BATCH, 0, stream>>>(bin, x, in_w, in_idx,
                                                     biases, cnt);
    ell_zero_kernel<<<1024, 256, 0, stream>>>(ellm);
    ell_build_kernel<<<(N_EDGES + 255) / 256, 256, 0, stream>>>(rows, cols, rec_w,
                                                                ellm, cnt);

    // 150 iterations; one wave per node, 4 nodes per block
    __half* hA = h0;
    __half* hB = h1;
    for (int t = 0; t < ITERS; t++) {
        step_kernel<<<N_NODES / 4, 256, 0, stream>>>(hA, hB, bin, biases,
                                                     (const int4*)ellm, cnt);
        __half* tmp = hA; hA = hB; hB = tmp;
    }

    // ITERS even -> final state in h0
    output_kernel<<<BATCH, N_OUT, 0, stream>>>(h0, oidx, out_w, out);
}